// Round 9
// baseline (328.558 us; speedup 1.0000x reference)
//
#include <hip/hip_runtime.h>
#include <hip/hip_bf16.h>
#include <hip/hip_cooperative_groups.h>

namespace cg = cooperative_groups;

#define EPSV 1e-5f

typedef __attribute__((ext_vector_type(8))) short short8;
typedef __attribute__((ext_vector_type(4))) float f32x4;
typedef __attribute__((ext_vector_type(2))) float f32x2;
typedef __attribute__((ext_vector_type(4))) unsigned u32x4;

#define LDSU32 __attribute__((address_space(3))) unsigned int
#define GLBU32 const __attribute__((address_space(1))) unsigned int

// ws layout: S (150,994,944 B) | w2 (1,179,648 B) | st (2,048 B)
#define S_BYTES  150994944ull
#define W2_BYTES 1179648ull

// w_deform (o, g*64+c, kk) fp32 -> w2 bf16 [o][g*576 + k*64 + c]; zero st.
__global__ __launch_bounds__(256) void wt2_kernel(const float* __restrict__ wd,
                                                  __hip_bfloat16* __restrict__ w2,
                                                  float* __restrict__ st) {
  int idx = blockIdx.x * 256 + threadIdx.x;   // 589824 = o*2304 + g*576 + k*64 + c
  int c  = idx & 63;
  int r  = idx >> 6;          // o*36 + g*9 + k
  int k  = r % 9;
  int r2 = r / 9;             // o*4 + g
  int g  = r2 & 3;
  int o  = r2 >> 2;
  w2[idx] = __float2bfloat16(wd[(o * 256 + g * 64 + c) * 9 + k]);
  if (blockIdx.x < 2) st[blockIdx.x * 256 + threadIdx.x] = 0.f;
}

static __device__ __forceinline__ f32x2 unpk(unsigned u) {
  union { unsigned i; float f; } lo, hi;
  lo.i = u << 16;
  hi.i = u & 0xffff0000u;
  return (f32x2){lo.f, hi.f};
}

// LDS-staged sampler (unchanged from R8): block = (b, g, 2-row band).
__global__ __launch_bounds__(256, 2) void sample_kernel(
    const float* __restrict__ x, const float* __restrict__ shp,
    const float* __restrict__ woff, __hip_bfloat16* __restrict__ S) {
  __shared__ __align__(16) unsigned short sX[8 * 64 * 72];  // [row][px][72] 73.7 KB

  const int b  = blockIdx.x & 7;              // XCD swizzle: batch -> XCD
  const int r2 = blockIdx.x >> 3;             // 0..127
  const int g  = r2 & 3;
  const int h0 = (r2 >> 2) << 1;              // band start row (2 rows/block)
  const int t  = threadIdx.x;
  const int px = t & 63;
  const int cq = t >> 6;                      // 0..3

  {
    const float* xg = x + ((size_t)(b * 256 + g * 64) << 12);
#pragma unroll
    for (int p = 0; p < 4; ++p) {
      const int c0 = (p << 4) + (cq << 2);
      const float* xc = xg + ((size_t)c0 << 12);
#pragma unroll
      for (int r = 0; r < 8; ++r) {
        int grow = min(max(h0 - 3 + r, 0), 63);
        int gi = (grow << 6) + px;
        float f0 = xc[gi];
        float f1 = xc[gi + 4096];
        float f2 = xc[gi + 8192];
        float f3 = xc[gi + 12288];
        __hip_bfloat162 pk0 = __float22bfloat162_rn(make_float2(f0, f1));
        __hip_bfloat162 pk1 = __float22bfloat162_rn(make_float2(f2, f3));
        *(uint2*)&sX[r * 4608 + px * 72 + c0] =
            make_uint2(*(unsigned*)&pk0, *(unsigned*)&pk1);
      }
    }
  }

  float a[2][4];
#pragma unroll
  for (int hh = 0; hh < 2; ++hh)
#pragma unroll
    for (int cc = 0; cc < 4; ++cc)
      a[hh][cc] = shp[((size_t)(b * 4 + cc) << 12) + ((h0 + hh) << 6) + px];

  __syncthreads();

  const int cs = cq << 4;
  unsigned short* Sb = (unsigned short*)S;

  for (int hh = 0; hh < 2; ++hh) {
    const int h = h0 + hh;
    for (int k = 0; k < 9; ++k) {
      const int gk = g * 9 + k;
      const float* wp = woff + gk * 8;
      float dy = wp[0]*a[hh][0] + wp[1]*a[hh][1] + wp[2]*a[hh][2] + wp[3]*a[hh][3];
      float dx = wp[4]*a[hh][0] + wp[5]*a[hh][1] + wp[6]*a[hh][2] + wp[7]*a[hh][3];
      float py  = dy + (float)(h + k / 3 - 1);
      float pxp = dx + (float)(px + k % 3 - 1);
      float y0f = floorf(py), x0f = floorf(pxp);
      float ly = py - y0f, lx = pxp - x0f;
      int y0 = (int)y0f, x0 = (int)x0f;
      float m_y0 = (y0 >=  0 && y0 <= 63) ? 1.f : 0.f;
      float m_y1 = (y0 >= -1 && y0 <= 62) ? 1.f : 0.f;
      float m_x0 = (x0 >=  0 && x0 <= 63) ? 1.f : 0.f;
      float m_x1 = (x0 >= -1 && x0 <= 62) ? 1.f : 0.f;
      float w00 = (1.f - ly) * (1.f - lx) * m_y0 * m_x0;
      float w01 = (1.f - ly) * lx         * m_y0 * m_x1;
      float w10 = ly         * (1.f - lx) * m_y1 * m_x0;
      float w11 = ly         * lx         * m_y1 * m_x1;
      int yc0 = min(max(y0, 0), 63),     yc1 = min(max(y0 + 1, 0), 63);
      int xc0 = min(max(x0, 0), 63),     xc1 = min(max(x0 + 1, 0), 63);
      int ry0 = min(max(yc0 - (h0 - 3), 0), 7);
      int ry1 = min(max(yc1 - (h0 - 3), 0), 7);

      const uint4* q00 = (const uint4*)&sX[ry0 * 4608 + xc0 * 72 + cs];
      const uint4* q01 = (const uint4*)&sX[ry0 * 4608 + xc1 * 72 + cs];
      const uint4* q10 = (const uint4*)&sX[ry1 * 4608 + xc0 * 72 + cs];
      const uint4* q11 = (const uint4*)&sX[ry1 * 4608 + xc1 * 72 + cs];
      uint4 A0 = q00[0], A1 = q00[1];
      uint4 B0 = q01[0], B1 = q01[1];
      uint4 C0 = q10[0], C1 = q10[1];
      uint4 D0 = q11[0], D1 = q11[1];
      unsigned ua[8] = {A0.x, A0.y, A0.z, A0.w, A1.x, A1.y, A1.z, A1.w};
      unsigned ub[8] = {B0.x, B0.y, B0.z, B0.w, B1.x, B1.y, B1.z, B1.w};
      unsigned uc[8] = {C0.x, C0.y, C0.z, C0.w, C1.x, C1.y, C1.z, C1.w};
      unsigned ud[8] = {D0.x, D0.y, D0.z, D0.w, D1.x, D1.y, D1.z, D1.w};

      unsigned o[8];
#pragma unroll
      for (int j = 0; j < 8; ++j) {
        f32x2 v = unpk(ua[j]) * w00 + unpk(ub[j]) * w01
                + unpk(uc[j]) * w10 + unpk(ud[j]) * w11;
        __hip_bfloat162 pk = __float22bfloat162_rn(make_float2(v.x, v.y));
        o[j] = *(unsigned*)&pk;
      }
      size_t so = (size_t)((b << 12) + (h << 6) + px) * 2304 + g * 576 + k * 64 + cs;
      ((u32x4*)(Sb + so))[0] = (u32x4){o[0], o[1], o[2], o[3]};
      ((u32x4*)(Sb + so))[1] = (u32x4){o[4], o[5], o[6], o[7]};
    }
  }
}

// Cooperative GEMM + fused GroupNorm/affine/ReLU.
// out[b][o][n] = GN(sum_K w2[o][K] * S^T[b*4096+n][K]). BK=64, xor-swizzled
// LDS (swizzle applied on the global source address; global_load_lds forces
// lane-contiguous LDS slots). Stats via atomics -> grid.sync -> normalize in
// registers -> single store.
__global__ __launch_bounds__(256, 2) void gemm_kernel(
    const __hip_bfloat16* __restrict__ Sp, const __hip_bfloat16* __restrict__ w2,
    float* __restrict__ out, float* __restrict__ st,
    const float* __restrict__ gamma, const float* __restrict__ beta) {
  __shared__ __align__(16) unsigned short sA[128 * 64];   // 16 KB
  __shared__ __align__(16) unsigned short sB[128 * 64];   // 16 KB
  const int b  = blockIdx.x & 7;              // XCD swizzle
  const int r2 = blockIdx.x >> 3;             // 0..63
  const int mt = r2 & 1;
  const int nt = r2 >> 1;                     // 0..31
  const int o0 = mt << 7, n0 = nt << 7;
  const int t = threadIdx.x;
  const int wv = t >> 6, lane = t & 63;
  const int quad = lane >> 4, l15 = lane & 15;
  const int wm = wv & 1, wn = wv >> 1;

  const unsigned short* Ab = (const unsigned short*)w2 + (size_t)o0 * 2304;
  const unsigned short* Bb = (const unsigned short*)Sp + (size_t)((b << 12) + n0) * 2304;

  f32x4 acc[4][4];
#pragma unroll
  for (int mo = 0; mo < 4; ++mo)
#pragma unroll
    for (int np = 0; np < 4; ++np) acc[mo][np] = (f32x4){0.f, 0.f, 0.f, 0.f};

  for (int k0 = 0; k0 < 2304; k0 += 64) {
#pragma unroll
    for (int i = 0; i < 4; ++i) {
      const int f = (i << 8) + t;             // LDS slot (16B units), lane-ordered
      const int row = f >> 3;
      const int seg = (f & 7) ^ (row & 7);    // xor-swizzle on SOURCE segment
      __builtin_amdgcn_global_load_lds(
          (GLBU32*)(Ab + (size_t)row * 2304 + k0 + (seg << 3)),
          (LDSU32*)(sA + (i << 11) + (wv << 9)), 16, 0, 0);
      __builtin_amdgcn_global_load_lds(
          (GLBU32*)(Bb + (size_t)row * 2304 + k0 + (seg << 3)),
          (LDSU32*)(sB + (i << 11) + (wv << 9)), 16, 0, 0);
    }
    __syncthreads();
    short8 af[2][4];
#pragma unroll
    for (int ks = 0; ks < 2; ++ks)
#pragma unroll
      for (int mo = 0; mo < 4; ++mo) {
        const int row = (wm << 6) + (mo << 4) + l15;
        const int seg = ((ks << 2) + quad) ^ (row & 7);
        af[ks][mo] = *(const short8*)(sA + (row << 6) + (seg << 3));
      }
#pragma unroll
    for (int np = 0; np < 4; ++np)
#pragma unroll
      for (int ks = 0; ks < 2; ++ks) {
        const int row = (wn << 6) + (np << 4) + l15;
        const int seg = ((ks << 2) + quad) ^ (row & 7);
        short8 bf = *(const short8*)(sB + (row << 6) + (seg << 3));
#pragma unroll
        for (int mo = 0; mo < 4; ++mo)
          acc[mo][np] = __builtin_amdgcn_mfma_f32_16x16x32_bf16(af[ks][mo], bf, acc[mo][np], 0, 0, 0);
      }
    __syncthreads();
  }

  // GN partial stats (group = 8 consecutive o)
#pragma unroll
  for (int mo = 0; mo < 4; ++mo) {
    float s = 0.f, q = 0.f;
#pragma unroll
    for (int np = 0; np < 4; ++np)
#pragma unroll
      for (int r = 0; r < 4; ++r) { float v = acc[mo][np][r]; s += v; q += v * v; }
#pragma unroll
    for (int m = 1; m < 16; m <<= 1) { s += __shfl_xor(s, m, 64); q += __shfl_xor(q, m, 64); }
    if (l15 == 0) {
      int gid = (b << 5) + (mt << 4) + (wm << 3) + (mo << 1) + (quad >> 1);
      atomicAdd(&st[gid], s);
      atomicAdd(&st[256 + gid], q);
    }
  }

  __threadfence();
  cg::this_grid().sync();

  // Normalize + affine + ReLU in registers, single store.
  const float invn = 1.f / 32768.f;
  float* ob = out + ((size_t)((b << 8) + o0 + (wm << 6)) << 12) + n0 + (wn << 6);
#pragma unroll
  for (int mo = 0; mo < 4; ++mo) {
    const int gid = (b << 5) + (mt << 4) + (wm << 3) + (mo << 1) + (quad >> 1);
    float mu  = st[gid] * invn;
    float var = st[256 + gid] * invn - mu * mu;
    float rs  = rsqrtf(var + EPSV);
#pragma unroll
    for (int r = 0; r < 4; ++r) {
      const int o = o0 + (wm << 6) + (mo << 4) + (quad << 2) + r;
      float ga = gamma[o] * rs;
      float be = beta[o] - mu * ga;
#pragma unroll
      for (int np = 0; np < 4; ++np)
        ob[((size_t)((mo << 4) + (quad << 2) + r) << 12) + (np << 4) + l15] =
            fmaxf(fmaf(acc[mo][np][r], ga, be), 0.f);
    }
  }
}

extern "C" void kernel_launch(void* const* d_in, const int* in_sizes, int n_in,
                              void* d_out, int out_size, void* d_ws, size_t ws_size,
                              hipStream_t stream) {
  const float* x     = (const float*)d_in[0];
  const float* shp   = (const float*)d_in[1];
  const float* woff  = (const float*)d_in[2];
  const float* wdef  = (const float*)d_in[3];
  const float* gamma = (const float*)d_in[4];
  const float* beta  = (const float*)d_in[5];
  float* out = (float*)d_out;
  __hip_bfloat16* S  = (__hip_bfloat16*)d_ws;
  __hip_bfloat16* w2 = (__hip_bfloat16*)((char*)d_ws + S_BYTES);
  float* st          = (float*)((char*)d_ws + S_BYTES + W2_BYTES);

  hipLaunchKernelGGL(wt2_kernel,    dim3(2304), dim3(256), 0, stream, wdef, w2, st);
  hipLaunchKernelGGL(sample_kernel, dim3(1024), dim3(256), 0, stream, x, shp, woff, S);

  const __hip_bfloat16* Sc = S; const __hip_bfloat16* w2c = w2;
  void* args[] = {(void*)&Sc, (void*)&w2c, (void*)&out, (void*)&st,
                  (void*)&gamma, (void*)&beta};
  hipLaunchCooperativeKernel((void*)gemm_kernel, dim3(512), dim3(256), args, 0, stream);
}

// Round 10
// 230.175 us; speedup vs baseline: 1.4274x; 1.4274x over previous
//
#include <hip/hip_runtime.h>
#include <hip/hip_bf16.h>

#define EPSV 1e-5f

typedef __attribute__((ext_vector_type(8))) short short8;
typedef __attribute__((ext_vector_type(4))) float f32x4;
typedef __attribute__((ext_vector_type(2))) float f32x2;
typedef __attribute__((ext_vector_type(4))) unsigned u32x4;

#define LDSU32 __attribute__((address_space(3))) unsigned int
#define GLBU32 const __attribute__((address_space(1))) unsigned int

// ws layout: S (150,994,944 B) | w2 (1,179,648 B) | st (2,048 B)
#define S_BYTES  150994944ull
#define W2_BYTES 1179648ull

// w_deform (o, g*64+c, kk) fp32 -> w2 bf16 [o][g*576 + k*64 + c]; zero st.
__global__ __launch_bounds__(256) void wt2_kernel(const float* __restrict__ wd,
                                                  __hip_bfloat16* __restrict__ w2,
                                                  float* __restrict__ st) {
  int idx = blockIdx.x * 256 + threadIdx.x;   // 589824 = o*2304 + g*576 + k*64 + c
  int c  = idx & 63;
  int r  = idx >> 6;          // o*36 + g*9 + k
  int k  = r % 9;
  int r2 = r / 9;             // o*4 + g
  int g  = r2 & 3;
  int o  = r2 >> 2;
  w2[idx] = __float2bfloat16(wd[(o * 256 + g * 64 + c) * 9 + k]);
  if (blockIdx.x < 2) st[blockIdx.x * 256 + threadIdx.x] = 0.f;
}

static __device__ __forceinline__ f32x2 unpk(unsigned u) {
  union { unsigned i; float f; } lo, hi;
  lo.i = u << 16;
  hi.i = u & 0xffff0000u;
  return (f32x2){lo.f, hi.f};
}

// LDS-staged sampler (R8, unchanged): block = (b, g, 2-row band).
__global__ __launch_bounds__(256, 2) void sample_kernel(
    const float* __restrict__ x, const float* __restrict__ shp,
    const float* __restrict__ woff, __hip_bfloat16* __restrict__ S) {
  __shared__ __align__(16) unsigned short sX[8 * 64 * 72];  // [row][px][72] 73.7 KB

  const int b  = blockIdx.x & 7;              // XCD swizzle: batch -> XCD
  const int r2 = blockIdx.x >> 3;             // 0..127
  const int g  = r2 & 3;
  const int h0 = (r2 >> 2) << 1;              // band start row (2 rows/block)
  const int t  = threadIdx.x;
  const int px = t & 63;
  const int cq = t >> 6;                      // 0..3

  {
    const float* xg = x + ((size_t)(b * 256 + g * 64) << 12);
#pragma unroll
    for (int p = 0; p < 4; ++p) {
      const int c0 = (p << 4) + (cq << 2);
      const float* xc = xg + ((size_t)c0 << 12);
#pragma unroll
      for (int r = 0; r < 8; ++r) {
        int grow = min(max(h0 - 3 + r, 0), 63);
        int gi = (grow << 6) + px;
        float f0 = xc[gi];
        float f1 = xc[gi + 4096];
        float f2 = xc[gi + 8192];
        float f3 = xc[gi + 12288];
        __hip_bfloat162 pk0 = __float22bfloat162_rn(make_float2(f0, f1));
        __hip_bfloat162 pk1 = __float22bfloat162_rn(make_float2(f2, f3));
        *(uint2*)&sX[r * 4608 + px * 72 + c0] =
            make_uint2(*(unsigned*)&pk0, *(unsigned*)&pk1);
      }
    }
  }

  float a[2][4];
#pragma unroll
  for (int hh = 0; hh < 2; ++hh)
#pragma unroll
    for (int cc = 0; cc < 4; ++cc)
      a[hh][cc] = shp[((size_t)(b * 4 + cc) << 12) + ((h0 + hh) << 6) + px];

  __syncthreads();

  const int cs = cq << 4;
  unsigned short* Sb = (unsigned short*)S;

  for (int hh = 0; hh < 2; ++hh) {
    const int h = h0 + hh;
    for (int k = 0; k < 9; ++k) {
      const int gk = g * 9 + k;
      const float* wp = woff + gk * 8;
      float dy = wp[0]*a[hh][0] + wp[1]*a[hh][1] + wp[2]*a[hh][2] + wp[3]*a[hh][3];
      float dx = wp[4]*a[hh][0] + wp[5]*a[hh][1] + wp[6]*a[hh][2] + wp[7]*a[hh][3];
      float py  = dy + (float)(h + k / 3 - 1);
      float pxp = dx + (float)(px + k % 3 - 1);
      float y0f = floorf(py), x0f = floorf(pxp);
      float ly = py - y0f, lx = pxp - x0f;
      int y0 = (int)y0f, x0 = (int)x0f;
      float m_y0 = (y0 >=  0 && y0 <= 63) ? 1.f : 0.f;
      float m_y1 = (y0 >= -1 && y0 <= 62) ? 1.f : 0.f;
      float m_x0 = (x0 >=  0 && x0 <= 63) ? 1.f : 0.f;
      float m_x1 = (x0 >= -1 && x0 <= 62) ? 1.f : 0.f;
      float w00 = (1.f - ly) * (1.f - lx) * m_y0 * m_x0;
      float w01 = (1.f - ly) * lx         * m_y0 * m_x1;
      float w10 = ly         * (1.f - lx) * m_y1 * m_x0;
      float w11 = ly         * lx         * m_y1 * m_x1;
      int yc0 = min(max(y0, 0), 63),     yc1 = min(max(y0 + 1, 0), 63);
      int xc0 = min(max(x0, 0), 63),     xc1 = min(max(x0 + 1, 0), 63);
      int ry0 = min(max(yc0 - (h0 - 3), 0), 7);
      int ry1 = min(max(yc1 - (h0 - 3), 0), 7);

      const uint4* q00 = (const uint4*)&sX[ry0 * 4608 + xc0 * 72 + cs];
      const uint4* q01 = (const uint4*)&sX[ry0 * 4608 + xc1 * 72 + cs];
      const uint4* q10 = (const uint4*)&sX[ry1 * 4608 + xc0 * 72 + cs];
      const uint4* q11 = (const uint4*)&sX[ry1 * 4608 + xc1 * 72 + cs];
      uint4 A0 = q00[0], A1 = q00[1];
      uint4 B0 = q01[0], B1 = q01[1];
      uint4 C0 = q10[0], C1 = q10[1];
      uint4 D0 = q11[0], D1 = q11[1];
      unsigned ua[8] = {A0.x, A0.y, A0.z, A0.w, A1.x, A1.y, A1.z, A1.w};
      unsigned ub[8] = {B0.x, B0.y, B0.z, B0.w, B1.x, B1.y, B1.z, B1.w};
      unsigned uc[8] = {C0.x, C0.y, C0.z, C0.w, C1.x, C1.y, C1.z, C1.w};
      unsigned ud[8] = {D0.x, D0.y, D0.z, D0.w, D1.x, D1.y, D1.z, D1.w};

      unsigned o[8];
#pragma unroll
      for (int j = 0; j < 8; ++j) {
        f32x2 v = unpk(ua[j]) * w00 + unpk(ub[j]) * w01
                + unpk(uc[j]) * w10 + unpk(ud[j]) * w11;
        __hip_bfloat162 pk = __float22bfloat162_rn(make_float2(v.x, v.y));
        o[j] = *(unsigned*)&pk;
      }
      size_t so = (size_t)((b << 12) + (h << 6) + px) * 2304 + g * 576 + k * 64 + cs;
      ((u32x4*)(Sb + so))[0] = (u32x4){o[0], o[1], o[2], o[3]};
      ((u32x4*)(Sb + so))[1] = (u32x4){o[4], o[5], o[6], o[7]};
    }
  }
}

// GEMM: out[b][o][n] = sum_K w2[o][K] * S^T[b*4096+n][K], K=2304.
// 128x128 tile, BK=64, xor-swizzled LDS (source-side), explicit DOUBLE-BUFFER
// with raw s_barrier + manual s_waitcnt vmcnt(8): next iter's 8 global_load_lds
// stay in flight across this iter's MFMAs (never vmcnt(0) until the last iter).
// GN partial stats via atomics; separate norm pass (coop fusion regressed, R9).
__global__ __launch_bounds__(256, 2) void gemm_kernel(
    const __hip_bfloat16* __restrict__ Sp, const __hip_bfloat16* __restrict__ w2,
    float* __restrict__ out, float* __restrict__ st) {
  __shared__ __align__(16) unsigned short sA[2][128 * 64];   // 2 x 16 KB
  __shared__ __align__(16) unsigned short sB[2][128 * 64];   // 2 x 16 KB
  const int b  = blockIdx.x & 7;              // XCD swizzle
  const int r2 = blockIdx.x >> 3;             // 0..63
  const int mt = r2 & 1;
  const int nt = r2 >> 1;                     // 0..31
  const int o0 = mt << 7, n0 = nt << 7;
  const int t = threadIdx.x;
  const int wv = t >> 6, lane = t & 63;
  const int quad = lane >> 4, l15 = lane & 15;
  const int wm = wv & 1, wn = wv >> 1;

  const unsigned short* Ab = (const unsigned short*)w2 + (size_t)o0 * 2304;
  const unsigned short* Bb = (const unsigned short*)Sp + (size_t)((b << 12) + n0) * 2304;

  f32x4 acc[4][4];
#pragma unroll
  for (int mo = 0; mo < 4; ++mo)
#pragma unroll
    for (int np = 0; np < 4; ++np) acc[mo][np] = (f32x4){0.f, 0.f, 0.f, 0.f};

  // issue one K-slab (BK=64) into buffer `buf`: 8 x 16B loads per thread
  auto issue = [&](int k0, int buf) {
#pragma unroll
    for (int i = 0; i < 4; ++i) {
      const int f = (i << 8) + t;             // LDS slot (16B units), lane-ordered
      const int row = f >> 3;
      const int seg = (f & 7) ^ (row & 7);    // xor-swizzle on SOURCE segment
      __builtin_amdgcn_global_load_lds(
          (GLBU32*)(Ab + (size_t)row * 2304 + k0 + (seg << 3)),
          (LDSU32*)(&sA[buf][(i << 11) + (wv << 9)]), 16, 0, 0);
      __builtin_amdgcn_global_load_lds(
          (GLBU32*)(Bb + (size_t)row * 2304 + k0 + (seg << 3)),
          (LDSU32*)(&sB[buf][(i << 11) + (wv << 9)]), 16, 0, 0);
    }
  };

  issue(0, 0);
  for (int it = 0; it < 36; ++it) {
    const int cur = it & 1;
    if (it < 35) {
      issue((it + 1) << 6, cur ^ 1);
      asm volatile("s_waitcnt vmcnt(8)" ::: "memory");  // own buf[cur] loads done
    } else {
      asm volatile("s_waitcnt vmcnt(0)" ::: "memory");
    }
    asm volatile("s_barrier" ::: "memory");             // everyone's buf[cur] ready

    short8 af[2][4];
#pragma unroll
    for (int ks = 0; ks < 2; ++ks)
#pragma unroll
      for (int mo = 0; mo < 4; ++mo) {
        const int row = (wm << 6) + (mo << 4) + l15;
        const int seg = ((ks << 2) + quad) ^ (row & 7);
        af[ks][mo] = *(const short8*)(&sA[cur][(row << 6) + (seg << 3)]);
      }
#pragma unroll
    for (int np = 0; np < 4; ++np)
#pragma unroll
      for (int ks = 0; ks < 2; ++ks) {
        const int row = (wn << 6) + (np << 4) + l15;
        const int seg = ((ks << 2) + quad) ^ (row & 7);
        short8 bf = *(const short8*)(&sB[cur][(row << 6) + (seg << 3)]);
#pragma unroll
        for (int mo = 0; mo < 4; ++mo)
          acc[mo][np] = __builtin_amdgcn_mfma_f32_16x16x32_bf16(af[ks][mo], bf, acc[mo][np], 0, 0, 0);
      }
    if (it < 35)
      asm volatile("s_barrier" ::: "memory");           // done reading buf[cur]; safe to overwrite next iter
  }

  // GN partial stats (group = 8 consecutive o)
#pragma unroll
  for (int mo = 0; mo < 4; ++mo) {
    float s = 0.f, q = 0.f;
#pragma unroll
    for (int np = 0; np < 4; ++np)
#pragma unroll
      for (int r = 0; r < 4; ++r) { float v = acc[mo][np][r]; s += v; q += v * v; }
#pragma unroll
    for (int m = 1; m < 16; m <<= 1) { s += __shfl_xor(s, m, 64); q += __shfl_xor(q, m, 64); }
    if (l15 == 0) {
      int gid = (b << 5) + (mt << 4) + (wm << 3) + (mo << 1) + (quad >> 1);
      atomicAdd(&st[gid], s);
      atomicAdd(&st[256 + gid], q);
    }
  }

  // Epilogue: C/D layout col(n)=l15, row(o)=quad*4+r. Temporal (norm re-reads).
  float* ob = out + ((size_t)((b << 8) + o0 + (wm << 6)) << 12) + n0 + (wn << 6);
#pragma unroll
  for (int mo = 0; mo < 4; ++mo)
#pragma unroll
    for (int np = 0; np < 4; ++np)
#pragma unroll
      for (int r = 0; r < 4; ++r)
        ob[((size_t)((mo << 4) + (quad << 2) + r) << 12) + (np << 4) + l15] = acc[mo][np][r];
}

// Normalize + affine + ReLU from atomic sums (full-line nt store).
__global__ __launch_bounds__(256) void norm_kernel(float* __restrict__ o,
    const float* __restrict__ st, const float* __restrict__ gamma,
    const float* __restrict__ beta) {
  int idx = blockIdx.x * 256 + threadIdx.x;    // float4s: 2,097,152
  f32x4* p = (f32x4*)o;
  int c = (idx >> 10) & 255;
  int b = idx >> 18;
  int g = b * 32 + (c >> 3);
  const float invn = 1.f / 32768.f;
  float mu  = st[g] * invn;
  float var = st[256 + g] * invn - mu * mu;
  float ga = gamma[c] * rsqrtf(var + EPSV);
  float be = beta[c] - mu * ga;
  f32x4 v = p[idx];
  v.x = fmaxf(fmaf(v.x, ga, be), 0.f);
  v.y = fmaxf(fmaf(v.y, ga, be), 0.f);
  v.z = fmaxf(fmaf(v.z, ga, be), 0.f);
  v.w = fmaxf(fmaf(v.w, ga, be), 0.f);
  __builtin_nontemporal_store(v, &p[idx]);
}

extern "C" void kernel_launch(void* const* d_in, const int* in_sizes, int n_in,
                              void* d_out, int out_size, void* d_ws, size_t ws_size,
                              hipStream_t stream) {
  const float* x     = (const float*)d_in[0];
  const float* shp   = (const float*)d_in[1];
  const float* woff  = (const float*)d_in[2];
  const float* wdef  = (const float*)d_in[3];
  const float* gamma = (const float*)d_in[4];
  const float* beta  = (const float*)d_in[5];
  float* out = (float*)d_out;
  __hip_bfloat16* S  = (__hip_bfloat16*)d_ws;
  __hip_bfloat16* w2 = (__hip_bfloat16*)((char*)d_ws + S_BYTES);
  float* st          = (float*)((char*)d_ws + S_BYTES + W2_BYTES);

  hipLaunchKernelGGL(wt2_kernel,    dim3(2304), dim3(256), 0, stream, wdef, w2, st);
  hipLaunchKernelGGL(sample_kernel, dim3(1024), dim3(256), 0, stream, x, shp, woff, S);
  hipLaunchKernelGGL(gemm_kernel,   dim3(512),  dim3(256), 0, stream, S, w2, out, st);
  hipLaunchKernelGGL(norm_kernel,   dim3(8192), dim3(256), 0, stream, out, st, gamma, beta);
}